// Round 13
// baseline (187.128 us; speedup 1.0000x reference)
//
#include <hip/hip_runtime.h>
#include <hip/hip_fp16.h>
#include <cmath>

#define Dd 512
#define Hh 1024
#define Rr 32
#define Ss 16
#define Bb 4
#define Ll 2048
#define Mm 8192   // B*L
#define NCc 64    // scan chunks
#define Tt 32     // L / NCc
#define NGg 16    // combine groups
#define GC  4     // chunks per group

typedef short bf16x8 __attribute__((ext_vector_type(8)));
typedef short s16x8 __attribute__((ext_vector_type(8)));
typedef float f32x4 __attribute__((ext_vector_type(4)));

static __device__ __forceinline__ float fsigmoid(float x){ return 1.0f/(1.0f+__expf(-x)); }
static __device__ __forceinline__ float fsilu(float x){ return x/(1.0f+__expf(-x)); }
static __device__ __forceinline__ ushort f2bf(float f){
  uint32_t u = __float_as_uint(f);
  uint32_t r = (u + 0x7fffu + ((u>>16)&1u)) >> 16;
  return (ushort)r;
}
static __device__ __forceinline__ float bf2f(ushort u){
  return __uint_as_float(((uint32_t)u) << 16);
}
static __device__ __forceinline__ float powbexp(float base, int e){
  float pw = (e&1) ? base : 1.0f;
  float b2 = base*base;
  if (e&2) pw *= b2;
  b2 *= b2;
  if (e&4) pw *= b2;
  b2 *= b2;
  if (e&8) pw *= b2;
  b2 *= b2;
  if (e&16) pw *= b2;
  return pw;
}
static __device__ __forceinline__ void gload16(const void* g, void* l){
  __builtin_amdgcn_global_load_lds(
      (const __attribute__((address_space(1))) uint32_t*)g,
      (__attribute__((address_space(3))) uint32_t*)l, 16, 0, 0);
}

// weight bf16 pool offsets (elements)
#define OFF_WU  0          // Wcat_u [1024,1024]: cols 0..511 Wa_u, 512..1023 Wgb
#define OFF_WV  1048576    // Wcat_v [1024,1024]: cols 0..511 Wa_v, 512..1023 Wgc
#define OFF_Wc  2097152    // Wc [64,1024]
#define OFF_Wi  2162688    // Wi [512,1024]
#define WTOT    2686976

// ---------------- x -> act[:, 0:512] bf16 cast -------------------------------
__global__ __launch_bounds__(256) void cast_x(
    const float* __restrict__ in, ushort* __restrict__ act)
{
  int i = (blockIdx.x*256 + threadIdx.x)*4;    // over M*512
  int m = i >> 9, c = i & 511;
  float4 v = *(const float4*)(in + i);
  ushort4 o; o.x=f2bf(v.x); o.y=f2bf(v.y); o.z=f2bf(v.z); o.w=f2bf(v.w);
  *(ushort4*)(act + (size_t)m*1024 + c) = o;
}

// ---------------- fused weight cast into concat layouts ----------------------
__global__ __launch_bounds__(256) void cast_weights(
    const float* __restrict__ Wa, const float* __restrict__ Wgb,
    const float* __restrict__ Wgc, const float* __restrict__ Wc,
    const float* __restrict__ Wi, ushort* __restrict__ out)
{
  int i4 = (blockIdx.x*256 + threadIdx.x)*4;
  if (i4 >= WTOT) return;
  const float* src;
  if (i4 < OFF_WV) {
    int n = i4 >> 10, col = i4 & 1023;
    src = (col < 512) ? (Wa + (size_t)n*512 + col) : (Wgb + (size_t)n*512 + col - 512);
  } else if (i4 < OFF_Wc) {
    int idx = i4 - OFF_WV;
    int n = idx >> 10, col = idx & 1023;
    src = (col < 512) ? (Wa + (size_t)(1024+n)*512 + col) : (Wgc + (size_t)n*512 + col - 512);
  } else if (i4 < OFF_Wi) {
    src = Wc + (i4 - OFF_Wc);
  } else {
    src = Wi + (i4 - OFF_Wi);
  }
  float4 v = *(const float4*)src;
  ushort4 o; o.x=f2bf(v.x); o.y=f2bf(v.y); o.z=f2bf(v.z); o.w=f2bf(v.w);
  *(ushort4*)(out + i4) = o;
}

// -------- LayerNorm: one row per wave, bf16 out into act[:, 512:1024] --------
__global__ __launch_bounds__(256) void ln_kernel(
    const float* __restrict__ ctx, const float* __restrict__ w,
    const float* __restrict__ bch, ushort* __restrict__ out)
{
  int wave = threadIdx.x >> 6, lane = threadIdx.x & 63;
  int row = (blockIdx.x << 2) + wave;
  const float* src = ctx + (size_t)row * Dd;
  float4 v0 = *(const float4*)(src + lane*4);
  float4 v1 = *(const float4*)(src + 256 + lane*4);
  float s  = v0.x+v0.y+v0.z+v0.w+v1.x+v1.y+v1.z+v1.w;
  float s2 = v0.x*v0.x+v0.y*v0.y+v0.z*v0.z+v0.w*v0.w
           + v1.x*v1.x+v1.y*v1.y+v1.z*v1.z+v1.w*v1.w;
  #pragma unroll
  for (int off=32; off>=1; off>>=1){ s += __shfl_down(s,off); s2 += __shfl_down(s2,off); }
  s = __shfl(s,0); s2 = __shfl(s2,0);
  float mu = s * (1.0f/Dd);
  float rs = rsqrtf(fmaxf(s2*(1.0f/Dd) - mu*mu, 0.0f) + 1e-5f);
  ushort* dst = out + (size_t)row*1024;
  int c0 = lane*4;
  ushort4 o;
  o.x=f2bf((v0.x-mu)*rs*w[c0+0]+bch[c0+0]);
  o.y=f2bf((v0.y-mu)*rs*w[c0+1]+bch[c0+1]);
  o.z=f2bf((v0.z-mu)*rs*w[c0+2]+bch[c0+2]);
  o.w=f2bf((v0.w-mu)*rs*w[c0+3]+bch[c0+3]);
  *(ushort4*)(dst + c0) = o;
  int c1 = 256 + lane*4;
  o.x=f2bf((v1.x-mu)*rs*w[c1+0]+bch[c1+0]);
  o.y=f2bf((v1.y-mu)*rs*w[c1+1]+bch[c1+1]);
  o.z=f2bf((v1.z-mu)*rs*w[c1+2]+bch[c1+2]);
  o.w=f2bf((v1.w-mu)*rs*w[c1+3]+bch[c1+3]);
  *(ushort4*)(dst + c1) = o;
}

// ====== merged u/v GEMM, 8 waves, BM=256 BN=64; 1-D grid 1024, XCD swizzle ===
// side 0: u_pre = (x@Wa_u^T + ba_u) * (1 + sigmoid(c@Wgb^T + bgb))
// side 1: v     = (x@Wa_v^T + ba_v) + (c@Wgc^T + bgc)
// 8 waves 4x2: wave tile 64x32; accZ[4][2]+accP[4][2]; 80KB LDS, 2 blocks/CU.
__global__ __launch_bounds__(512, 4) void gemm_uv64(
    const ushort* __restrict__ act, const ushort* __restrict__ wbf,
    const float* __restrict__ ba, const float* __restrict__ bgb,
    const float* __restrict__ bgc,
    ushort* __restrict__ u_pre, ushort* __restrict__ v_out)
{
  __shared__ ushort As1[256*64], As2[256*64];
  __shared__ ushort Ws1[64*64],  Ws2[64*64];
  int tid = threadIdx.x;
  int wave = tid >> 6, lane = tid & 63;
  // XCD swizzle: XCD x owns bx in [x*4, x*4+4) (A-panel locality)
  int flat = blockIdx.x;
  int swz  = (flat & 7) * 128 + (flat >> 3);
  int bx   = swz >> 5;
  int rem  = swz & 31;
  int by   = rem >> 1;
  int side = rem & 1;
  int m0 = bx * 256;
  int n0 = by * 64;
  const ushort* W = wbf + (side ? OFF_WV : OFF_WU);
  const float* b1 = side ? (ba + Hh) : ba;
  const float* b2 = side ? bgc : bgb;
  ushort* OUT = side ? v_out : u_pre;
  int wr = wave >> 1, wc = wave & 1;

  f32x4 accZ[4][2], accP[4][2];
  #pragma unroll
  for (int i=0;i<4;i++)
  #pragma unroll
  for (int j=0;j<2;j++){ accZ[i][j]=(f32x4){0.f,0.f,0.f,0.f}; accP[i][j]=(f32x4){0.f,0.f,0.f,0.f}; }

  for (int k0 = 0; k0 < 512; k0 += 64) {
    #pragma unroll
    for (int i=0;i<4;i++){
      int off  = i*8192 + tid*16;
      int row  = off >> 7;
      int slot = (off >> 4) & 7;
      int ch   = slot ^ (row & 7);
      gload16(act + (size_t)(m0+row)*1024 + k0 + ch*8,       (char*)As1 + off);
      gload16(act + (size_t)(m0+row)*1024 + 512 + k0 + ch*8, (char*)As2 + off);
    }
    {
      int off  = tid*16;
      int row  = off >> 7;
      int slot = (off >> 4) & 7;
      int ch   = slot ^ (row & 7);
      gload16(W + (size_t)(n0+row)*1024 + k0 + ch*8,       (char*)Ws1 + off);
      gload16(W + (size_t)(n0+row)*1024 + 512 + k0 + ch*8, (char*)Ws2 + off);
    }
    __syncthreads();
    bf16x8 af[4][2], bfr[2][2];
    #pragma unroll
    for (int ks=0;ks<2;ks++){
      int chb = ks*4 + (lane>>4);
      #pragma unroll
      for (int mi=0;mi<4;mi++){
        int r = wr*64 + mi*16 + (lane&15);
        int slot = chb ^ (r&7);
        af[mi][ks] = *(const bf16x8*)((const char*)As1 + r*128 + slot*16);
      }
      #pragma unroll
      for (int ni=0;ni<2;ni++){
        int r = wc*32 + ni*16 + (lane&15);
        int slot = chb ^ (r&7);
        bfr[ni][ks] = *(const bf16x8*)((const char*)Ws1 + r*128 + slot*16);
      }
    }
    #pragma unroll
    for (int ks=0;ks<2;ks++)
    #pragma unroll
    for (int mi=0;mi<4;mi++)
    #pragma unroll
    for (int ni=0;ni<2;ni++)
      accZ[mi][ni] = __builtin_amdgcn_mfma_f32_16x16x32_bf16(af[mi][ks], bfr[ni][ks], accZ[mi][ni], 0,0,0);
    #pragma unroll
    for (int ks=0;ks<2;ks++){
      int chb = ks*4 + (lane>>4);
      #pragma unroll
      for (int mi=0;mi<4;mi++){
        int r = wr*64 + mi*16 + (lane&15);
        int slot = chb ^ (r&7);
        af[mi][ks] = *(const bf16x8*)((const char*)As2 + r*128 + slot*16);
      }
      #pragma unroll
      for (int ni=0;ni<2;ni++){
        int r = wc*32 + ni*16 + (lane&15);
        int slot = chb ^ (r&7);
        bfr[ni][ks] = *(const bf16x8*)((const char*)Ws2 + r*128 + slot*16);
      }
    }
    #pragma unroll
    for (int ks=0;ks<2;ks++)
    #pragma unroll
    for (int mi=0;mi<4;mi++)
    #pragma unroll
    for (int ni=0;ni<2;ni++)
      accP[mi][ni] = __builtin_amdgcn_mfma_f32_16x16x32_bf16(af[mi][ks], bfr[ni][ks], accP[mi][ni], 0,0,0);
    __syncthreads();
  }

  #pragma unroll
  for (int mi=0;mi<4;mi++){
    int mbase = m0 + wr*64 + mi*16 + (lane>>4)*4;
    #pragma unroll
    for (int ni=0;ni<2;ni++){
      int n = n0 + wc*32 + ni*16 + (lane&15);
      float bb1 = b1[n], bb2 = b2[n];
      #pragma unroll
      for (int j=0;j<4;j++){
        float z = accZ[mi][ni][j] + bb1;
        float p = accP[mi][ni][j] + bb2;
        float o = side ? (z + p) : z*(1.0f + fsigmoid(p));
        OUT[(size_t)(mbase+j)*Hh + n] = f2bf(o);
      }
    }
  }
}

// ====== out GEMM, BN=64: C[M,512]; 1-D grid 512, XCD swizzle =================
__global__ __launch_bounds__(256, 2) void gemm_out64(
    const ushort* __restrict__ A, const ushort* __restrict__ W,
    const float* __restrict__ bias, float* __restrict__ C)
{
  __shared__ ushort As[128*64];
  __shared__ ushort Bs[64*64];
  int tid = threadIdx.x;
  int wave = tid >> 6, lane = tid & 63;
  int flat = blockIdx.x;
  int swz  = (flat & 7) * 64 + (flat >> 3);
  int m0 = (swz >> 3) * 128;
  int n0 = (swz & 7) * 64;
  int wr = wave >> 1, wc = wave & 1;

  f32x4 acc[4][2];
  #pragma unroll
  for (int i=0;i<4;i++)
  #pragma unroll
  for (int j=0;j<2;j++) acc[i][j] = (f32x4){0.f,0.f,0.f,0.f};

  for (int k0 = 0; k0 < 1024; k0 += 64) {
    #pragma unroll
    for (int i=0;i<4;i++){
      int off  = i*4096 + wave*1024 + lane*16;
      int row  = off >> 7;
      int slot = (off >> 4) & 7;
      int ch   = slot ^ (row & 7);
      gload16(A + (size_t)(m0+row)*1024 + k0 + ch*8, (char*)As + off);
      if (i < 2)
        gload16(W + (size_t)(n0+row)*1024 + k0 + ch*8, (char*)Bs + off);
    }
    __syncthreads();
    bf16x8 af[4][2], bfr[2][2];
    #pragma unroll
    for (int ks=0;ks<2;ks++){
      int chb = ks*4 + (lane>>4);
      #pragma unroll
      for (int mi=0;mi<4;mi++){
        int r = wr*64 + mi*16 + (lane&15);
        int slot = chb ^ (r&7);
        af[mi][ks] = *(const bf16x8*)((const char*)As + r*128 + slot*16);
      }
      #pragma unroll
      for (int ni=0;ni<2;ni++){
        int r = wc*32 + ni*16 + (lane&15);
        int slot = chb ^ (r&7);
        bfr[ni][ks] = *(const bf16x8*)((const char*)Bs + r*128 + slot*16);
      }
    }
    #pragma unroll
    for (int ks=0;ks<2;ks++)
    #pragma unroll
    for (int mi=0;mi<4;mi++)
    #pragma unroll
    for (int ni=0;ni<2;ni++)
      acc[mi][ni] = __builtin_amdgcn_mfma_f32_16x16x32_bf16(af[mi][ks], bfr[ni][ks], acc[mi][ni], 0,0,0);
    __syncthreads();
  }
  #pragma unroll
  for (int mi=0;mi<4;mi++){
    int mbase = m0 + wr*64 + mi*16 + (lane>>4)*4;
    #pragma unroll
    for (int ni=0;ni<2;ni++){
      int n = n0 + wc*32 + ni*16 + (lane&15);
      float bv = bias[n];
      #pragma unroll
      for (int j=0;j<4;j++)
        C[(size_t)(mbase+j)*Dd + n] = acc[mi][ni][j] + bv;
    }
  }
}

// ====== zc GEMM split-K: grid (64, 4); partials f32 [4][M][64] ===============
__global__ __launch_bounds__(256, 2) void gemm_n64s(
    const ushort* __restrict__ A, const ushort* __restrict__ W,
    float* __restrict__ Cp)
{
  __shared__ ushort As[128*64];
  __shared__ ushort Bs[64*64];
  int tid = threadIdx.x;
  int wave = tid >> 6, lane = tid & 63;
  int m0 = blockIdx.x * 128;
  int ks0 = blockIdx.y * 256;
  float* Cout = Cp + (size_t)blockIdx.y * Mm * 64;

  f32x4 acc[2][4];
  #pragma unroll
  for (int i=0;i<2;i++)
  #pragma unroll
  for (int j=0;j<4;j++) acc[i][j] = (f32x4){0.f,0.f,0.f,0.f};

  for (int kk = 0; kk < 256; kk += 64) {
    int k0 = ks0 + kk;
    #pragma unroll
    for (int i=0;i<4;i++){
      int off  = i*4096 + wave*1024 + lane*16;
      int row  = off >> 7;
      int slot = (off >> 4) & 7;
      int ch   = slot ^ (row & 7);
      gload16(A + (size_t)(m0+row)*1024 + k0 + ch*8, (char*)As + off);
      if (i < 2)
        gload16(W + (size_t)row*1024 + k0 + ch*8, (char*)Bs + off);
    }
    __syncthreads();
    bf16x8 af[2][2], bfr[4][2];
    #pragma unroll
    for (int ks=0;ks<2;ks++){
      int chb = ks*4 + (lane>>4);
      #pragma unroll
      for (int mi=0;mi<2;mi++){
        int r = wave*32 + mi*16 + (lane&15);
        int slot = chb ^ (r&7);
        af[mi][ks] = *(const bf16x8*)((const char*)As + r*128 + slot*16);
      }
      #pragma unroll
      for (int ni=0;ni<4;ni++){
        int r = ni*16 + (lane&15);
        int slot = chb ^ (r&7);
        bfr[ni][ks] = *(const bf16x8*)((const char*)Bs + r*128 + slot*16);
      }
    }
    #pragma unroll
    for (int ks=0;ks<2;ks++)
    #pragma unroll
    for (int mi=0;mi<2;mi++)
    #pragma unroll
    for (int ni=0;ni<4;ni++)
      acc[mi][ni] = __builtin_amdgcn_mfma_f32_16x16x32_bf16(af[mi][ks], bfr[ni][ks], acc[mi][ni], 0,0,0);
    __syncthreads();
  }
  #pragma unroll
  for (int mi=0;mi<2;mi++){
    int mbase = m0 + wave*32 + mi*16 + (lane>>4)*4;
    #pragma unroll
    for (int ni=0;ni<4;ni++){
      int n = ni*16 + (lane&15);
      #pragma unroll
      for (int j=0;j<4;j++)
        Cout[(size_t)(mbase+j)*64 + n] = acc[mi][ni][j];
    }
  }
}

// --------- causal depthwise conv1d (k=3) + silu; bf16x8 per thread -----------
__global__ __launch_bounds__(256) void conv_kernel(
    const ushort* __restrict__ u, const float* __restrict__ cw,
    const float* __restrict__ cb, ushort* __restrict__ outb)
{
  int i = blockIdx.x*256 + threadIdx.x;     // over M*(H/8)
  int row = i >> 7;                          // global row (b*L + t)
  int h0  = (i & 127) * 8;
  int t   = row & (Ll-1);
  const ushort* p2 = u + (size_t)row*Hh + h0;
  s16x8 a2 = *(const s16x8*)p2;
  s16x8 a1 = (t >= 1) ? *(const s16x8*)(p2 - Hh)   : (s16x8){0,0,0,0,0,0,0,0};
  s16x8 a0 = (t >= 2) ? *(const s16x8*)(p2 - 2*Hh) : (s16x8){0,0,0,0,0,0,0,0};
  s16x8 o;
  #pragma unroll
  for (int j=0;j<8;j++){
    int h = h0 + j;
    float acc = fmaf(bf2f((ushort)a0[j]), cw[h*3+0],
                fmaf(bf2f((ushort)a1[j]), cw[h*3+1],
                fmaf(bf2f((ushort)a2[j]), cw[h*3+2], cb[h])));
    o[j] = (short)f2bf(fsilu(acc));
  }
  *(s16x8*)(outb + (size_t)row*Hh + h0) = o;
}

// ================= chunk-parallel selective scan =============================
// zc read directly from split-K partials Cp (sums 4 during staging).
__global__ __launch_bounds__(256) void scanA_kernel(
    const ushort* __restrict__ u_bf, const float* __restrict__ Cp,
    const float* __restrict__ We, const float* __restrict__ be,
    float* __restrict__ P1out, ushort* __restrict__ Xlout,
    __half* __restrict__ dt_out)
{
  __shared__ float zs[Tt][64];               // cols 0..31 dt-rank, 32..47 = b
  __shared__ ushort u_s[Tt][256];
  int tid = threadIdx.x;
  int bc = blockIdx.x >> 2;                  // b*NC + c
  int hq = blockIdx.x & 3;
  int h  = hq*256 + tid;
  int b  = bc >> 6, c = bc & (NCc-1);
  size_t rowbase = (size_t)(b*Ll + c*Tt);
  #pragma unroll
  for (int i=0;i<2;i++){
    int f = tid + i*256;
    int row = f >> 4, col = (f & 15)*4;
    size_t gi = (rowbase + row)*64 + col;
    f32x4 pa = *(const f32x4*)(Cp + gi);
    f32x4 pb = *(const f32x4*)(Cp + (size_t)Mm*64 + gi);
    f32x4 pc = *(const f32x4*)(Cp + (size_t)2*Mm*64 + gi);
    f32x4 pd = *(const f32x4*)(Cp + (size_t)3*Mm*64 + gi);
    *(f32x4*)&zs[row][col] = (pa+pb)+(pc+pd);
  }
  #pragma unroll
  for (int i=0;i<4;i++){
    int idx = tid + i*256;
    int row = idx >> 5, ch = idx & 31;
    *(uint4*)&u_s[row][ch*8] = *(const uint4*)(u_bf + (rowbase + row)*Hh + hq*256 + ch*8);
  }
  float we_[Rr];
  #pragma unroll
  for (int r=0;r<Rr;r+=4) *(float4*)&we_[r] = *(const float4*)&We[h*Rr+r];
  float bev = be[h];
  __syncthreads();
  float x_[Ss];
  #pragma unroll
  for (int s=0;s<Ss;s++) x_[s]=0.0f;
  float P1 = 1.0f;
  size_t rowidx = rowbase*Hh + h;
  for (int tt=0; tt<Tt; ++tt){
    float u = bf2f(u_s[tt][tid]);
    float d0=0.f,d1=0.f,d2=0.f,d3=0.f;
    #pragma unroll
    for (int q=0;q<8;q++){
      f32x4 zv = *(const f32x4*)&zs[tt][q*4];
      d0 = fmaf(zv[0], we_[q*4+0], d0);
      d1 = fmaf(zv[1], we_[q*4+1], d1);
      d2 = fmaf(zv[2], we_[q*4+2], d2);
      d3 = fmaf(zv[3], we_[q*4+3], d3);
    }
    float acc = bev + ((d0+d1)+(d2+d3));
    float t  = __expf(acc);
    float e1 = __fdividef(1.0f, 1.0f + t);
    float dtv = (acc > 20.0f) ? acc : __logf(1.0f + t);
    dt_out[rowidx] = __float2half(dtv);
    rowidx += Hh;
    float dtu = dtv*u;
    P1 *= e1;
    float a2 = e1*e1;
    float a4 = a2*a2;
    float w0=e1, w1=a2, w2=a2*e1, w3=a4;
    #pragma unroll
    for (int grp=0; grp<4; ++grp){
      int s0 = grp*4;
      f32x4 bv = *(const f32x4*)&zs[tt][32+s0];
      x_[s0+0] = fmaf(w0, x_[s0+0], dtu*bv[0]);
      x_[s0+1] = fmaf(w1, x_[s0+1], dtu*bv[1]);
      x_[s0+2] = fmaf(w2, x_[s0+2], dtu*bv[2]);
      x_[s0+3] = fmaf(w3, x_[s0+3], dtu*bv[3]);
      if (grp < 3){ w0*=a4; w1*=a4; w2*=a4; w3*=a4; }
    }
  }
  P1out[(size_t)bc*Hh + h] = P1;
  size_t base = ((size_t)bc*Ss)*Hh + h;
  #pragma unroll
  for (int s=0;s<Ss;s++) Xlout[base + (size_t)s*Hh] = f2bf(x_[s]);
}

// ===== hierarchical combine: C1 group-aggregate, C2 across groups, C3 replay =
__global__ __launch_bounds__(256) void scanC1_kernel(
    const float* __restrict__ P1b, const ushort* __restrict__ Xl,
    float* __restrict__ Pg, float* __restrict__ Xg)
{
  int tid  = threadIdx.x;
  int hblk = blockIdx.x & 3;
  int rest = blockIdx.x >> 2;
  int s = rest & 15;
  int g = (rest >> 4) & 15;
  int b = rest >> 8;
  int h = hblk*256 + tid;
  int e = s+1;
  float X = 0.0f, Pp = 1.0f;
  #pragma unroll
  for (int c8=0;c8<GC;c8++){
    int c = g*GC + c8;
    float P1 = P1b[((size_t)(b*NCc+c))*Hh + h];
    float pw = powbexp(P1, e);
    float Xv = bf2f(Xl[(((size_t)(b*NCc+c))*Ss + s)*Hh + h]);
    X = fmaf(pw, X, Xv);
    Pp *= P1;
  }
  size_t oidx = (((size_t)(b*Ss+s))*NGg + g)*Hh + h;
  Pg[oidx] = powbexp(Pp, e);
  Xg[oidx] = X;
}

__global__ __launch_bounds__(256) void scanC2_kernel(
    const float* __restrict__ Pg, float* __restrict__ Xg)
{
  int gidx = blockIdx.x*256 + threadIdx.x;   // ((b*S+s)*H + h)
  int h  = gidx & (Hh-1);
  int bs = gidx >> 10;
  float xi = 0.0f;
  size_t base = (size_t)bs*NGg*Hh + h;
  for (int g=0; g<NGg; g++){
    size_t idx = base + (size_t)g*Hh;
    float Pv = Pg[idx], Xv = Xg[idx];
    Xg[idx] = xi;
    xi = fmaf(Pv, xi, Xv);
  }
}

__global__ __launch_bounds__(256) void scanC3_kernel(
    const float* __restrict__ P1b, const float* __restrict__ Xg,
    ushort* __restrict__ Xl)
{
  int tid  = threadIdx.x;
  int hblk = blockIdx.x & 3;
  int rest = blockIdx.x >> 2;
  int s = rest & 15;
  int g = (rest >> 4) & 15;
  int b = rest >> 8;
  int h = hblk*256 + tid;
  int e = s+1;
  float xi = Xg[(((size_t)(b*Ss+s))*NGg + g)*Hh + h];
  #pragma unroll
  for (int c8=0;c8<GC;c8++){
    int c = g*GC + c8;
    size_t idxL = (((size_t)(b*NCc+c))*Ss + s)*Hh + h;
    float Xv = bf2f(Xl[idxL]);
    Xl[idxL] = f2bf(xi);
    float P1 = P1b[((size_t)(b*NCc+c))*Hh + h];
    xi = fmaf(powbexp(P1, e), xi, Xv);
  }
}

// scanB: no dt-dot — loads precomputed dt (fp16); e1 = exp(-dt).
__global__ __launch_bounds__(256) void scanB_kernel(
    const ushort* __restrict__ u_bf, const float* __restrict__ Cp,
    const __half* __restrict__ dt_in, const ushort* __restrict__ v_bf,
    const float* __restrict__ g, const ushort* __restrict__ xinit,
    ushort* __restrict__ yv)
{
  __shared__ float zs[Tt][64];               // 32..47 b, 48..63 c (0..31 unused)
  __shared__ ushort u_s[Tt][256];
  __shared__ ushort v_s[Tt][256];
  __shared__ ushort dt_s[Tt][256];
  int tid = threadIdx.x;
  int bc = blockIdx.x >> 2;
  int hq = blockIdx.x & 3;
  int h  = hq*256 + tid;
  int b  = bc >> 6, c = bc & (NCc-1);
  size_t rowbase = (size_t)(b*Ll + c*Tt);
  #pragma unroll
  for (int i=0;i<2;i++){
    int f = tid + i*256;
    int row = f >> 3, col = 32 + (f & 7)*4;
    size_t gi = (rowbase + row)*64 + col;
    f32x4 pa = *(const f32x4*)(Cp + gi);
    f32x4 pb = *(const f32x4*)(Cp + (size_t)Mm*64 + gi);
    f32x4 pc = *(const f32x4*)(Cp + (size_t)2*Mm*64 + gi);
    f32x4 pd = *(const f32x4*)(Cp + (size_t)3*Mm*64 + gi);
    *(f32x4*)&zs[row][col] = (pa+pb)+(pc+pd);
  }
  #pragma unroll
  for (int i=0;i<4;i++){
    int idx = tid + i*256;
    int row = idx >> 5, ch = idx & 31;
    *(uint4*)&u_s[row][ch*8]  = *(const uint4*)(u_bf + (rowbase + row)*Hh + hq*256 + ch*8);
    *(uint4*)&v_s[row][ch*8]  = *(const uint4*)(v_bf + (rowbase + row)*Hh + hq*256 + ch*8);
    *(uint4*)&dt_s[row][ch*8] = *(const uint4*)((const ushort*)dt_in + (rowbase + row)*Hh + hq*256 + ch*8);
  }
  float gv = g[h];
  float x_[Ss];
  size_t base = ((size_t)bc*Ss)*Hh + h;
  #pragma unroll
  for (int s=0;s<Ss;s++) x_[s] = bf2f(xinit[base + (size_t)s*Hh]);
  __syncthreads();
  size_t rowidx = rowbase*Hh + h;
  for (int tt=0; tt<Tt; ++tt){
    float u  = bf2f(u_s[tt][tid]);
    float vv = bf2f(v_s[tt][tid]);
    ushort draw = dt_s[tt][tid];
    float dtv = __half2float(*(const __half*)&draw);
    float e1  = __expf(-dtv);
    float dtu = dtv*u;
    float a2 = e1*e1;
    float a4 = a2*a2;
    float w0=e1, w1=a2, w2=a2*e1, w3=a4;
    float y0=0.f,y1=0.f,y2=0.f,y3=0.f;
    #pragma unroll
    for (int grp=0; grp<4; ++grp){
      int s0 = grp*4;
      f32x4 bv = *(const f32x4*)&zs[tt][32+s0];
      f32x4 cv = *(const f32x4*)&zs[tt][48+s0];
      x_[s0+0] = fmaf(w0, x_[s0+0], dtu*bv[0]);
      x_[s0+1] = fmaf(w1, x_[s0+1], dtu*bv[1]);
      x_[s0+2] = fmaf(w2, x_[s0+2], dtu*bv[2]);
      x_[s0+3] = fmaf(w3, x_[s0+3], dtu*bv[3]);
      y0 = fmaf(x_[s0+0], cv[0], y0);
      y1 = fmaf(x_[s0+1], cv[1], y1);
      y2 = fmaf(x_[s0+2], cv[2], y2);
      y3 = fmaf(x_[s0+3], cv[3], y3);
      if (grp < 3){ w0*=a4; w1*=a4; w2*=a4; w3*=a4; }
    }
    float y = (y0+y1)+(y2+y3);
    yv[rowidx] = f2bf((y + u*gv) * fsilu(vv));
    rowidx += Hh;
  }
}

extern "C" void kernel_launch(void* const* d_in, const int* in_sizes, int n_in,
                              void* d_out, int out_size, void* d_ws, size_t ws_size,
                              hipStream_t stream) {
  const float* x      = (const float*)d_in[0];
  const float* ctx    = (const float*)d_in[1];
  const float* Wa     = (const float*)d_in[2];
  const float* ba     = (const float*)d_in[3];
  const float* conv_w = (const float*)d_in[4];
  const float* conv_b = (const float*)d_in[5];
  const float* Wc     = (const float*)d_in[6];
  const float* We     = (const float*)d_in[7];
  const float* be     = (const float*)d_in[8];
  const float* g      = (const float*)d_in[10];
  const float* Wi     = (const float*)d_in[11];
  const float* bi     = (const float*)d_in[12];
  const float* ln_w   = (const float*)d_in[13];
  const float* ln_b   = (const float*)d_in[14];
  const float* Wgb    = (const float*)d_in[15];
  const float* bgb    = (const float*)d_in[16];
  const float* Wgc    = (const float*)d_in[17];
  const float* bgc    = (const float*)d_in[18];
  float* out = (float*)d_out;

  // workspace layout (f32 element units):
  //  [ 0.. 4M)   u_pre_bf (8M bf16); yv_bf overlays after conv consumes it
  //  [ 4.. 8M)   v_bf     (8M bf16)
  //  [ 8..12M)   u_bf     (8M bf16)
  //  [12.5..13M) P1 f32 [B,NC,H]
  //  [13..15M)   Xl bf16 [B,NC,S,H] (4M elems; xinit in-place)
  //  [17..18M)   Pg f32 [B,S,NG,H]
  //  [18..19M)   Xg f32 [B,S,NG,H]
  //  [19..21M)   Cp f32 [4][M][64] split-K partials (zc never materialized)
  //  [22..26M)   act bf16 [M,1024]
  //  [26..27.4M) weight bf16 pool (concat layouts)
  //  [28..32M)   dt fp16 [M,H]
  const size_t MEG = 1024*1024;
  float*  ws       = (float*)d_ws;
  ushort* u_pre_bf = (ushort*)(ws);
  ushort* yv_bf    = (ushort*)(ws);
  ushort* v_bf     = (ushort*)(ws + 4*MEG);
  ushort* u_bf     = (ushort*)(ws + 8*MEG);
  float*  P1b      = ws + 12*MEG + MEG/2;
  ushort* Xl       = (ushort*)(ws + 13*MEG);
  float*  Pg       = ws + 17*MEG;
  float*  Xg       = ws + 18*MEG;
  float*  Cp       = ws + 19*MEG;
  ushort* act      = (ushort*)(ws + 22*MEG);
  ushort* wbf      = (ushort*)(ws + 26*MEG);
  __half* dt_h     = (__half*)(ws + 28*MEG);

  // casts + LN (both write into act)
  cast_x<<<(Mm*Dd)/1024, 256, 0, stream>>>(x, act);
  cast_weights<<<(WTOT/4)/256, 256, 0, stream>>>(Wa, Wgb, Wgc, Wc, Wi, wbf);
  ln_kernel<<<Mm/4, 256, 0, stream>>>(ctx, ln_w, ln_b, act + 512);
  // merged u/v GEMM: 8 waves, BM=256, XCD-swizzled 1-D grid
  gemm_uv64<<<1024, 512, 0, stream>>>(act, wbf, ba, bgb, bgc, u_pre_bf, v_bf);
  // causal depthwise conv + silu
  conv_kernel<<<(Mm*Hh/8)/256, 256, 0, stream>>>(u_pre_bf, conv_w, conv_b, u_bf);
  // zc split-K partials (summed in scan staging)
  gemm_n64s<<<dim3(Mm/128, 4), 256, 0, stream>>>(u_bf, wbf+OFF_Wc, Cp);
  // chunk-parallel scan with fused in-register dt + hierarchical combine
  scanA_kernel<<<(Bb*NCc*Hh)/256, 256, 0, stream>>>(u_bf, Cp, We, be, P1b, Xl, dt_h);
  scanC1_kernel<<<Bb*NGg*Ss*4, 256, 0, stream>>>(P1b, Xl, Pg, Xg);
  scanC2_kernel<<<(Bb*Ss*Hh)/256, 256, 0, stream>>>(Pg, Xg);
  scanC3_kernel<<<Bb*NGg*Ss*4, 256, 0, stream>>>(P1b, Xg, Xl);
  scanB_kernel<<<(Bb*NCc*Hh)/256, 256, 0, stream>>>(u_bf, Cp, dt_h, v_bf, g, Xl, yv_bf);
  // out = yv @ Wi^T + bi  (XCD-swizzled 1-D grid)
  gemm_out64<<<512, 256, 0, stream>>>(yv_bf, wbf+OFF_Wi, bi, out);
}

// Round 14
// 176.105 us; speedup vs baseline: 1.0626x; 1.0626x over previous
//
#include <hip/hip_runtime.h>
#include <hip/hip_fp16.h>
#include <cmath>

#define Dd 512
#define Hh 1024
#define Rr 32
#define Ss 16
#define Bb 4
#define Ll 2048
#define Mm 8192   // B*L
#define NCc 64    // scan chunks
#define Tt 32     // L / NCc
#define NGg 16    // combine groups
#define GC  4     // chunks per group

typedef short bf16x8 __attribute__((ext_vector_type(8)));
typedef short s16x8 __attribute__((ext_vector_type(8)));
typedef float f32x4 __attribute__((ext_vector_type(4)));
typedef _Float16 h2 __attribute__((ext_vector_type(2)));

static __device__ __forceinline__ float fsigmoid(float x){ return 1.0f/(1.0f+__expf(-x)); }
static __device__ __forceinline__ float fsilu(float x){ return x/(1.0f+__expf(-x)); }
static __device__ __forceinline__ ushort f2bf(float f){
  uint32_t u = __float_as_uint(f);
  uint32_t r = (u + 0x7fffu + ((u>>16)&1u)) >> 16;
  return (ushort)r;
}
static __device__ __forceinline__ float bf2f(ushort u){
  return __uint_as_float(((uint32_t)u) << 16);
}
static __device__ __forceinline__ float powbexp(float base, int e){
  float pw = (e&1) ? base : 1.0f;
  float b2 = base*base;
  if (e&2) pw *= b2;
  b2 *= b2;
  if (e&4) pw *= b2;
  b2 *= b2;
  if (e&8) pw *= b2;
  b2 *= b2;
  if (e&16) pw *= b2;
  return pw;
}
static __device__ __forceinline__ void gload16(const void* g, void* l){
  __builtin_amdgcn_global_load_lds(
      (const __attribute__((address_space(1))) uint32_t*)g,
      (__attribute__((address_space(3))) uint32_t*)l, 16, 0, 0);
}

// weight bf16 pool offsets (elements)
#define OFF_WU  0          // Wcat_u [1024,1024]: cols 0..511 Wa_u, 512..1023 Wgb
#define OFF_WV  1048576    // Wcat_v [1024,1024]: cols 0..511 Wa_v, 512..1023 Wgc
#define OFF_Wc  2097152    // Wc [64,1024]
#define OFF_Wi  2162688    // Wi [512,1024]
#define WTOT    2686976

// ======= fused prep: cast_x | LayerNorm | weight-cast | We->fp16 =============
// grid ranges: [0,4096) cast_x; [4096,6144) ln; [6144,8768) weights; [8768,8800) We
__global__ __launch_bounds__(256) void prep_kernel(
    const float* __restrict__ x, const float* __restrict__ ctx,
    const float* __restrict__ ln_w, const float* __restrict__ ln_b,
    const float* __restrict__ Wa, const float* __restrict__ Wgb,
    const float* __restrict__ Wgc, const float* __restrict__ Wc,
    const float* __restrict__ Wi, const float* __restrict__ We,
    ushort* __restrict__ act, ushort* __restrict__ wbf,
    _Float16* __restrict__ we_h)
{
  int bid = blockIdx.x;
  if (bid < 4096) {
    int i = (bid*256 + threadIdx.x)*4;    // over M*512
    int m = i >> 9, c = i & 511;
    float4 v = *(const float4*)(x + i);
    ushort4 o; o.x=f2bf(v.x); o.y=f2bf(v.y); o.z=f2bf(v.z); o.w=f2bf(v.w);
    *(ushort4*)(act + (size_t)m*1024 + c) = o;
  } else if (bid < 6144) {
    int wave = threadIdx.x >> 6, lane = threadIdx.x & 63;
    int row = ((bid-4096) << 2) + wave;
    const float* src = ctx + (size_t)row * Dd;
    float4 v0 = *(const float4*)(src + lane*4);
    float4 v1 = *(const float4*)(src + 256 + lane*4);
    float s  = v0.x+v0.y+v0.z+v0.w+v1.x+v1.y+v1.z+v1.w;
    float s2 = v0.x*v0.x+v0.y*v0.y+v0.z*v0.z+v0.w*v0.w
             + v1.x*v1.x+v1.y*v1.y+v1.z*v1.z+v1.w*v1.w;
    #pragma unroll
    for (int off=32; off>=1; off>>=1){ s += __shfl_down(s,off); s2 += __shfl_down(s2,off); }
    s = __shfl(s,0); s2 = __shfl(s2,0);
    float mu = s * (1.0f/Dd);
    float rs = rsqrtf(fmaxf(s2*(1.0f/Dd) - mu*mu, 0.0f) + 1e-5f);
    ushort* dst = act + 512 + (size_t)row*1024;
    int c0 = lane*4;
    ushort4 o;
    o.x=f2bf((v0.x-mu)*rs*ln_w[c0+0]+ln_b[c0+0]);
    o.y=f2bf((v0.y-mu)*rs*ln_w[c0+1]+ln_b[c0+1]);
    o.z=f2bf((v0.z-mu)*rs*ln_w[c0+2]+ln_b[c0+2]);
    o.w=f2bf((v0.w-mu)*rs*ln_w[c0+3]+ln_b[c0+3]);
    *(ushort4*)(dst + c0) = o;
    int c1 = 256 + lane*4;
    o.x=f2bf((v1.x-mu)*rs*ln_w[c1+0]+ln_b[c1+0]);
    o.y=f2bf((v1.y-mu)*rs*ln_w[c1+1]+ln_b[c1+1]);
    o.z=f2bf((v1.z-mu)*rs*ln_w[c1+2]+ln_b[c1+2]);
    o.w=f2bf((v1.w-mu)*rs*ln_w[c1+3]+ln_b[c1+3]);
    *(ushort4*)(dst + c1) = o;
  } else if (bid < 8768) {
    int i4 = ((bid-6144)*256 + threadIdx.x)*4;
    if (i4 >= WTOT) return;
    const float* src;
    if (i4 < OFF_WV) {
      int n = i4 >> 10, col = i4 & 1023;
      src = (col < 512) ? (Wa + (size_t)n*512 + col) : (Wgb + (size_t)n*512 + col - 512);
    } else if (i4 < OFF_Wc) {
      int idx = i4 - OFF_WV;
      int n = idx >> 10, col = idx & 1023;
      src = (col < 512) ? (Wa + (size_t)(1024+n)*512 + col) : (Wgc + (size_t)n*512 + col - 512);
    } else if (i4 < OFF_Wi) {
      src = Wc + (i4 - OFF_Wc);
    } else {
      src = Wi + (i4 - OFF_Wi);
    }
    float4 v = *(const float4*)src;
    ushort4 o; o.x=f2bf(v.x); o.y=f2bf(v.y); o.z=f2bf(v.z); o.w=f2bf(v.w);
    *(ushort4*)(wbf + i4) = o;
  } else {
    int i = ((bid-8768)*256 + threadIdx.x)*4;   // over 32768 elems
    float4 v = *(const float4*)(We + i);
    we_h[i+0] = (_Float16)v.x;
    we_h[i+1] = (_Float16)v.y;
    we_h[i+2] = (_Float16)v.z;
    we_h[i+3] = (_Float16)v.w;
  }
}

// ====== merged u/v GEMM, 8 waves, BM=256 BN=64; 1-D grid 1024, XCD swizzle ===
__global__ __launch_bounds__(512, 4) void gemm_uv64(
    const ushort* __restrict__ act, const ushort* __restrict__ wbf,
    const float* __restrict__ ba, const float* __restrict__ bgb,
    const float* __restrict__ bgc,
    ushort* __restrict__ u_pre, ushort* __restrict__ v_out)
{
  __shared__ ushort As1[256*64], As2[256*64];
  __shared__ ushort Ws1[64*64],  Ws2[64*64];
  int tid = threadIdx.x;
  int wave = tid >> 6, lane = tid & 63;
  int flat = blockIdx.x;
  int swz  = (flat & 7) * 128 + (flat >> 3);
  int bx   = swz >> 5;
  int rem  = swz & 31;
  int by   = rem >> 1;
  int side = rem & 1;
  int m0 = bx * 256;
  int n0 = by * 64;
  const ushort* W = wbf + (side ? OFF_WV : OFF_WU);
  const float* b1 = side ? (ba + Hh) : ba;
  const float* b2 = side ? bgc : bgb;
  ushort* OUT = side ? v_out : u_pre;
  int wr = wave >> 1, wc = wave & 1;

  f32x4 accZ[4][2], accP[4][2];
  #pragma unroll
  for (int i=0;i<4;i++)
  #pragma unroll
  for (int j=0;j<2;j++){ accZ[i][j]=(f32x4){0.f,0.f,0.f,0.f}; accP[i][j]=(f32x4){0.f,0.f,0.f,0.f}; }

  for (int k0 = 0; k0 < 512; k0 += 64) {
    #pragma unroll
    for (int i=0;i<4;i++){
      int off  = i*8192 + tid*16;
      int row  = off >> 7;
      int slot = (off >> 4) & 7;
      int ch   = slot ^ (row & 7);
      gload16(act + (size_t)(m0+row)*1024 + k0 + ch*8,       (char*)As1 + off);
      gload16(act + (size_t)(m0+row)*1024 + 512 + k0 + ch*8, (char*)As2 + off);
    }
    {
      int off  = tid*16;
      int row  = off >> 7;
      int slot = (off >> 4) & 7;
      int ch   = slot ^ (row & 7);
      gload16(W + (size_t)(n0+row)*1024 + k0 + ch*8,       (char*)Ws1 + off);
      gload16(W + (size_t)(n0+row)*1024 + 512 + k0 + ch*8, (char*)Ws2 + off);
    }
    __syncthreads();
    bf16x8 af[4][2], bfr[2][2];
    #pragma unroll
    for (int ks=0;ks<2;ks++){
      int chb = ks*4 + (lane>>4);
      #pragma unroll
      for (int mi=0;mi<4;mi++){
        int r = wr*64 + mi*16 + (lane&15);
        int slot = chb ^ (r&7);
        af[mi][ks] = *(const bf16x8*)((const char*)As1 + r*128 + slot*16);
      }
      #pragma unroll
      for (int ni=0;ni<2;ni++){
        int r = wc*32 + ni*16 + (lane&15);
        int slot = chb ^ (r&7);
        bfr[ni][ks] = *(const bf16x8*)((const char*)Ws1 + r*128 + slot*16);
      }
    }
    #pragma unroll
    for (int ks=0;ks<2;ks++)
    #pragma unroll
    for (int mi=0;mi<4;mi++)
    #pragma unroll
    for (int ni=0;ni<2;ni++)
      accZ[mi][ni] = __builtin_amdgcn_mfma_f32_16x16x32_bf16(af[mi][ks], bfr[ni][ks], accZ[mi][ni], 0,0,0);
    #pragma unroll
    for (int ks=0;ks<2;ks++){
      int chb = ks*4 + (lane>>4);
      #pragma unroll
      for (int mi=0;mi<4;mi++){
        int r = wr*64 + mi*16 + (lane&15);
        int slot = chb ^ (r&7);
        af[mi][ks] = *(const bf16x8*)((const char*)As2 + r*128 + slot*16);
      }
      #pragma unroll
      for (int ni=0;ni<2;ni++){
        int r = wc*32 + ni*16 + (lane&15);
        int slot = chb ^ (r&7);
        bfr[ni][ks] = *(const bf16x8*)((const char*)Ws2 + r*128 + slot*16);
      }
    }
    #pragma unroll
    for (int ks=0;ks<2;ks++)
    #pragma unroll
    for (int mi=0;mi<4;mi++)
    #pragma unroll
    for (int ni=0;ni<2;ni++)
      accP[mi][ni] = __builtin_amdgcn_mfma_f32_16x16x32_bf16(af[mi][ks], bfr[ni][ks], accP[mi][ni], 0,0,0);
    __syncthreads();
  }

  #pragma unroll
  for (int mi=0;mi<4;mi++){
    int mbase = m0 + wr*64 + mi*16 + (lane>>4)*4;
    #pragma unroll
    for (int ni=0;ni<2;ni++){
      int n = n0 + wc*32 + ni*16 + (lane&15);
      float bb1 = b1[n], bb2 = b2[n];
      #pragma unroll
      for (int j=0;j<4;j++){
        float z = accZ[mi][ni][j] + bb1;
        float p = accP[mi][ni][j] + bb2;
        float o = side ? (z + p) : z*(1.0f + fsigmoid(p));
        OUT[(size_t)(mbase+j)*Hh + n] = f2bf(o);
      }
    }
  }
}

// ====== out GEMM, BN=64: C[M,512]; 1-D grid 512, XCD swizzle =================
__global__ __launch_bounds__(256, 2) void gemm_out64(
    const ushort* __restrict__ A, const ushort* __restrict__ W,
    const float* __restrict__ bias, float* __restrict__ C)
{
  __shared__ ushort As[128*64];
  __shared__ ushort Bs[64*64];
  int tid = threadIdx.x;
  int wave = tid >> 6, lane = tid & 63;
  int flat = blockIdx.x;
  int swz  = (flat & 7) * 64 + (flat >> 3);
  int m0 = (swz >> 3) * 128;
  int n0 = (swz & 7) * 64;
  int wr = wave >> 1, wc = wave & 1;

  f32x4 acc[4][2];
  #pragma unroll
  for (int i=0;i<4;i++)
  #pragma unroll
  for (int j=0;j<2;j++) acc[i][j] = (f32x4){0.f,0.f,0.f,0.f};

  for (int k0 = 0; k0 < 1024; k0 += 64) {
    #pragma unroll
    for (int i=0;i<4;i++){
      int off  = i*4096 + wave*1024 + lane*16;
      int row  = off >> 7;
      int slot = (off >> 4) & 7;
      int ch   = slot ^ (row & 7);
      gload16(A + (size_t)(m0+row)*1024 + k0 + ch*8, (char*)As + off);
      if (i < 2)
        gload16(W + (size_t)(n0+row)*1024 + k0 + ch*8, (char*)Bs + off);
    }
    __syncthreads();
    bf16x8 af[4][2], bfr[2][2];
    #pragma unroll
    for (int ks=0;ks<2;ks++){
      int chb = ks*4 + (lane>>4);
      #pragma unroll
      for (int mi=0;mi<4;mi++){
        int r = wr*64 + mi*16 + (lane&15);
        int slot = chb ^ (r&7);
        af[mi][ks] = *(const bf16x8*)((const char*)As + r*128 + slot*16);
      }
      #pragma unroll
      for (int ni=0;ni<2;ni++){
        int r = wc*32 + ni*16 + (lane&15);
        int slot = chb ^ (r&7);
        bfr[ni][ks] = *(const bf16x8*)((const char*)Bs + r*128 + slot*16);
      }
    }
    #pragma unroll
    for (int ks=0;ks<2;ks++)
    #pragma unroll
    for (int mi=0;mi<4;mi++)
    #pragma unroll
    for (int ni=0;ni<2;ni++)
      acc[mi][ni] = __builtin_amdgcn_mfma_f32_16x16x32_bf16(af[mi][ks], bfr[ni][ks], acc[mi][ni], 0,0,0);
    __syncthreads();
  }
  #pragma unroll
  for (int mi=0;mi<4;mi++){
    int mbase = m0 + wr*64 + mi*16 + (lane>>4)*4;
    #pragma unroll
    for (int ni=0;ni<2;ni++){
      int n = n0 + wc*32 + ni*16 + (lane&15);
      float bv = bias[n];
      #pragma unroll
      for (int j=0;j<4;j++)
        C[(size_t)(mbase+j)*Dd + n] = acc[mi][ni][j] + bv;
    }
  }
}

// ====== zc GEMM split-K: grid (64, 4); partials f32 [4][M][64] ===============
__global__ __launch_bounds__(256, 2) void gemm_n64s(
    const ushort* __restrict__ A, const ushort* __restrict__ W,
    float* __restrict__ Cp)
{
  __shared__ ushort As[128*64];
  __shared__ ushort Bs[64*64];
  int tid = threadIdx.x;
  int wave = tid >> 6, lane = tid & 63;
  int m0 = blockIdx.x * 128;
  int ks0 = blockIdx.y * 256;
  float* Cout = Cp + (size_t)blockIdx.y * Mm * 64;

  f32x4 acc[2][4];
  #pragma unroll
  for (int i=0;i<2;i++)
  #pragma unroll
  for (int j=0;j<4;j++) acc[i][j] = (f32x4){0.f,0.f,0.f,0.f};

  for (int kk = 0; kk < 256; kk += 64) {
    int k0 = ks0 + kk;
    #pragma unroll
    for (int i=0;i<4;i++){
      int off  = i*4096 + wave*1024 + lane*16;
      int row  = off >> 7;
      int slot = (off >> 4) & 7;
      int ch   = slot ^ (row & 7);
      gload16(A + (size_t)(m0+row)*1024 + k0 + ch*8, (char*)As + off);
      if (i < 2)
        gload16(W + (size_t)row*1024 + k0 + ch*8, (char*)Bs + off);
    }
    __syncthreads();
    bf16x8 af[2][2], bfr[4][2];
    #pragma unroll
    for (int ks=0;ks<2;ks++){
      int chb = ks*4 + (lane>>4);
      #pragma unroll
      for (int mi=0;mi<2;mi++){
        int r = wave*32 + mi*16 + (lane&15);
        int slot = chb ^ (r&7);
        af[mi][ks] = *(const bf16x8*)((const char*)As + r*128 + slot*16);
      }
      #pragma unroll
      for (int ni=0;ni<4;ni++){
        int r = ni*16 + (lane&15);
        int slot = chb ^ (r&7);
        bfr[ni][ks] = *(const bf16x8*)((const char*)Bs + r*128 + slot*16);
      }
    }
    #pragma unroll
    for (int ks=0;ks<2;ks++)
    #pragma unroll
    for (int mi=0;mi<2;mi++)
    #pragma unroll
    for (int ni=0;ni<4;ni++)
      acc[mi][ni] = __builtin_amdgcn_mfma_f32_16x16x32_bf16(af[mi][ks], bfr[ni][ks], acc[mi][ni], 0,0,0);
    __syncthreads();
  }
  #pragma unroll
  for (int mi=0;mi<2;mi++){
    int mbase = m0 + wave*32 + mi*16 + (lane>>4)*4;
    #pragma unroll
    for (int ni=0;ni<4;ni++){
      int n = ni*16 + (lane&15);
      #pragma unroll
      for (int j=0;j<4;j++)
        Cout[(size_t)(mbase+j)*64 + n] = acc[mi][ni][j];
    }
  }
}

// --------- causal depthwise conv1d (k=3) + silu; bf16x8 per thread -----------
__global__ __launch_bounds__(256) void conv_kernel(
    const ushort* __restrict__ u, const float* __restrict__ cw,
    const float* __restrict__ cb, ushort* __restrict__ outb)
{
  int i = blockIdx.x*256 + threadIdx.x;     // over M*(H/8)
  int row = i >> 7;                          // global row (b*L + t)
  int h0  = (i & 127) * 8;
  int t   = row & (Ll-1);
  const ushort* p2 = u + (size_t)row*Hh + h0;
  s16x8 a2 = *(const s16x8*)p2;
  s16x8 a1 = (t >= 1) ? *(const s16x8*)(p2 - Hh)   : (s16x8){0,0,0,0,0,0,0,0};
  s16x8 a0 = (t >= 2) ? *(const s16x8*)(p2 - 2*Hh) : (s16x8){0,0,0,0,0,0,0,0};
  s16x8 o;
  #pragma unroll
  for (int j=0;j<8;j++){
    int h = h0 + j;
    float acc = fmaf(bf2f((ushort)a0[j]), cw[h*3+0],
                fmaf(bf2f((ushort)a1[j]), cw[h*3+1],
                fmaf(bf2f((ushort)a2[j]), cw[h*3+2], cb[h])));
    o[j] = (short)f2bf(fsilu(acc));
  }
  *(s16x8*)(outb + (size_t)row*Hh + h0) = o;
}

// ================= chunk-parallel selective scan =============================
// scanA: fp16 packed dt-dot (v_dot2); emits dt fp16 for scanB.
__global__ __launch_bounds__(256, 4) void scanA_kernel(
    const ushort* __restrict__ u_bf, const float* __restrict__ Cp,
    const _Float16* __restrict__ we_h, const float* __restrict__ be,
    float* __restrict__ P1out, ushort* __restrict__ Xlout,
    __half* __restrict__ dt_out)
{
  __shared__ uint  zh[Tt][16];               // cols 0..31 as packed half2
  __shared__ float zb[Tt][16];               // cols 32..47 (b)
  __shared__ ushort u_s[Tt][256];
  int tid = threadIdx.x;
  int bc = blockIdx.x >> 2;                  // b*NC + c
  int hq = blockIdx.x & 3;
  int h  = hq*256 + tid;
  int b  = bc >> 6, c = bc & (NCc-1);
  size_t rowbase = (size_t)(b*Ll + c*Tt);
  #pragma unroll
  for (int i=0;i<2;i++){
    int f = tid + i*256;
    int row = f >> 4, cg = f & 15;
    if (cg < 12) {
      size_t gi = (rowbase + row)*64 + cg*4;
      f32x4 pa = *(const f32x4*)(Cp + gi);
      f32x4 pb = *(const f32x4*)(Cp + (size_t)Mm*64 + gi);
      f32x4 pc = *(const f32x4*)(Cp + (size_t)2*Mm*64 + gi);
      f32x4 pd = *(const f32x4*)(Cp + (size_t)3*Mm*64 + gi);
      f32x4 sm = (pa+pb)+(pc+pd);
      if (cg < 8) {
        h2 lo = {(_Float16)sm[0], (_Float16)sm[1]};
        h2 hi = {(_Float16)sm[2], (_Float16)sm[3]};
        zh[row][cg*2+0] = __builtin_bit_cast(uint, lo);
        zh[row][cg*2+1] = __builtin_bit_cast(uint, hi);
      } else {
        *(f32x4*)&zb[row][(cg-8)*4] = sm;
      }
    }
  }
  #pragma unroll
  for (int i=0;i<4;i++){
    int idx = tid + i*256;
    int row = idx >> 5, ch = idx & 31;
    *(uint4*)&u_s[row][ch*8] = *(const uint4*)(u_bf + (rowbase + row)*Hh + hq*256 + ch*8);
  }
  uint we2u[16];
  #pragma unroll
  for (int q=0;q<4;q++)
    *(uint4*)&we2u[q*4] = *(const uint4*)(we_h + h*Rr + q*8);
  float bev = be[h];
  __syncthreads();
  float x_[Ss];
  #pragma unroll
  for (int s=0;s<Ss;s++) x_[s]=0.0f;
  float P1 = 1.0f;
  size_t rowidx = rowbase*Hh + h;
  for (int tt=0; tt<Tt; ++tt){
    float u = bf2f(u_s[tt][tid]);
    float da=0.f, db=0.f;
    uint4 za = *(const uint4*)&zh[tt][0];
    uint4 zb4 = *(const uint4*)&zh[tt][4];
    uint4 zc4 = *(const uint4*)&zh[tt][8];
    uint4 zd4 = *(const uint4*)&zh[tt][12];
    da = __builtin_amdgcn_fdot2(__builtin_bit_cast(h2, za.x), __builtin_bit_cast(h2, we2u[0]), da, false);
    db = __builtin_amdgcn_fdot2(__builtin_bit_cast(h2, za.y), __builtin_bit_cast(h2, we2u[1]), db, false);
    da = __builtin_amdgcn_fdot2(__builtin_bit_cast(h2, za.z), __builtin_bit_cast(h2, we2u[2]), da, false);
    db = __builtin_amdgcn_fdot2(__builtin_bit_cast(h2, za.w), __builtin_bit_cast(h2, we2u[3]), db, false);
    da = __builtin_amdgcn_fdot2(__builtin_bit_cast(h2, zb4.x), __builtin_bit_cast(h2, we2u[4]), da, false);
    db = __builtin_amdgcn_fdot2(__builtin_bit_cast(h2, zb4.y), __builtin_bit_cast(h2, we2u[5]), db, false);
    da = __builtin_amdgcn_fdot2(__builtin_bit_cast(h2, zb4.z), __builtin_bit_cast(h2, we2u[6]), da, false);
    db = __builtin_amdgcn_fdot2(__builtin_bit_cast(h2, zb4.w), __builtin_bit_cast(h2, we2u[7]), db, false);
    da = __builtin_amdgcn_fdot2(__builtin_bit_cast(h2, zc4.x), __builtin_bit_cast(h2, we2u[8]), da, false);
    db = __builtin_amdgcn_fdot2(__builtin_bit_cast(h2, zc4.y), __builtin_bit_cast(h2, we2u[9]), db, false);
    da = __builtin_amdgcn_fdot2(__builtin_bit_cast(h2, zc4.z), __builtin_bit_cast(h2, we2u[10]), da, false);
    db = __builtin_amdgcn_fdot2(__builtin_bit_cast(h2, zc4.w), __builtin_bit_cast(h2, we2u[11]), db, false);
    da = __builtin_amdgcn_fdot2(__builtin_bit_cast(h2, zd4.x), __builtin_bit_cast(h2, we2u[12]), da, false);
    db = __builtin_amdgcn_fdot2(__builtin_bit_cast(h2, zd4.y), __builtin_bit_cast(h2, we2u[13]), db, false);
    da = __builtin_amdgcn_fdot2(__builtin_bit_cast(h2, zd4.z), __builtin_bit_cast(h2, we2u[14]), da, false);
    db = __builtin_amdgcn_fdot2(__builtin_bit_cast(h2, zd4.w), __builtin_bit_cast(h2, we2u[15]), db, false);
    float acc = bev + (da + db);
    float t  = __expf(acc);
    float e1 = __fdividef(1.0f, 1.0f + t);
    float dtv = (acc > 20.0f) ? acc : __logf(1.0f + t);
    dt_out[rowidx] = __float2half(dtv);
    rowidx += Hh;
    float dtu = dtv*u;
    P1 *= e1;
    float a2 = e1*e1;
    float a4 = a2*a2;
    float w0=e1, w1=a2, w2=a2*e1, w3=a4;
    #pragma unroll
    for (int grp=0; grp<4; ++grp){
      int s0 = grp*4;
      f32x4 bv = *(const f32x4*)&zb[tt][s0];
      x_[s0+0] = fmaf(w0, x_[s0+0], dtu*bv[0]);
      x_[s0+1] = fmaf(w1, x_[s0+1], dtu*bv[1]);
      x_[s0+2] = fmaf(w2, x_[s0+2], dtu*bv[2]);
      x_[s0+3] = fmaf(w3, x_[s0+3], dtu*bv[3]);
      if (grp < 3){ w0*=a4; w1*=a4; w2*=a4; w3*=a4; }
    }
  }
  P1out[(size_t)bc*Hh + h] = P1;
  size_t base = ((size_t)bc*Ss)*Hh + h;
  #pragma unroll
  for (int s=0;s<Ss;s++) Xlout[base + (size_t)s*Hh] = f2bf(x_[s]);
}

// ===== hierarchical combine: C1 group-aggregate, C2 across groups, C3 replay =
__global__ __launch_bounds__(256) void scanC1_kernel(
    const float* __restrict__ P1b, const ushort* __restrict__ Xl,
    float* __restrict__ Pg, float* __restrict__ Xg)
{
  int tid  = threadIdx.x;
  int hblk = blockIdx.x & 3;
  int rest = blockIdx.x >> 2;
  int s = rest & 15;
  int g = (rest >> 4) & 15;
  int b = rest >> 8;
  int h = hblk*256 + tid;
  int e = s+1;
  float X = 0.0f, Pp = 1.0f;
  #pragma unroll
  for (int c8=0;c8<GC;c8++){
    int c = g*GC + c8;
    float P1 = P1b[((size_t)(b*NCc+c))*Hh + h];
    float pw = powbexp(P1, e);
    float Xv = bf2f(Xl[(((size_t)(b*NCc+c))*Ss + s)*Hh + h]);
    X = fmaf(pw, X, Xv);
    Pp *= P1;
  }
  size_t oidx = (((size_t)(b*Ss+s))*NGg + g)*Hh + h;
  Pg[oidx] = powbexp(Pp, e);
  Xg[oidx] = X;
}

__global__ __launch_bounds__(256) void scanC2_kernel(
    const float* __restrict__ Pg, float* __restrict__ Xg)
{
  int gidx = blockIdx.x*256 + threadIdx.x;   // ((b*S+s)*H + h)
  int h  = gidx & (Hh-1);
  int bs = gidx >> 10;
  float xi = 0.0f;
  size_t base = (size_t)bs*NGg*Hh + h;
  for (int g=0; g<NGg; g++){
    size_t idx = base + (size_t)g*Hh;
    float Pv = Pg[idx], Xv = Xg[idx];
    Xg[idx] = xi;
    xi = fmaf(Pv, xi, Xv);
  }
}

__global__ __launch_bounds__(256) void scanC3_kernel(
    const float* __restrict__ P1b, const float* __restrict__ Xg,
    ushort* __restrict__ Xl)
{
  int tid  = threadIdx.x;
  int hblk = blockIdx.x & 3;
  int rest = blockIdx.x >> 2;
  int s = rest & 15;
  int g = (rest >> 4) & 15;
  int b = rest >> 8;
  int h = hblk*256 + tid;
  int e = s+1;
  float xi = Xg[(((size_t)(b*Ss+s))*NGg + g)*Hh + h];
  #pragma unroll
  for (int c8=0;c8<GC;c8++){
    int c = g*GC + c8;
    size_t idxL = (((size_t)(b*NCc+c))*Ss + s)*Hh + h;
    float Xv = bf2f(Xl[idxL]);
    Xl[idxL] = f2bf(xi);
    float P1 = P1b[((size_t)(b*NCc+c))*Hh + h];
    xi = fmaf(powbexp(P1, e), xi, Xv);
  }
}

// scanB: reads dt fp16 from global (coalesced, L2-hot); b/c staged in LDS.
__global__ __launch_bounds__(256, 4) void scanB_kernel(
    const ushort* __restrict__ u_bf, const float* __restrict__ Cp,
    const __half* __restrict__ dt_in, const ushort* __restrict__ v_bf,
    const float* __restrict__ g, const ushort* __restrict__ xinit,
    ushort* __restrict__ yv)
{
  __shared__ float zb[Tt][16], zcc[Tt][16];
  __shared__ ushort u_s[Tt][256];
  __shared__ ushort v_s[Tt][256];
  int tid = threadIdx.x;
  int bc = blockIdx.x >> 2;
  int hq = blockIdx.x & 3;
  int h  = hq*256 + tid;
  int b  = bc >> 6, c = bc & (NCc-1);
  size_t rowbase = (size_t)(b*Ll + c*Tt);
  {
    int row = tid >> 3, cg = tid & 7;       // cols 32 + cg*4
    size_t gi = (rowbase + row)*64 + 32 + cg*4;
    f32x4 pa = *(const f32x4*)(Cp + gi);
    f32x4 pb = *(const f32x4*)(Cp + (size_t)Mm*64 + gi);
    f32x4 pc = *(const f32x4*)(Cp + (size_t)2*Mm*64 + gi);
    f32x4 pd = *(const f32x4*)(Cp + (size_t)3*Mm*64 + gi);
    f32x4 sm = (pa+pb)+(pc+pd);
    if (cg < 4) *(f32x4*)&zb[row][cg*4] = sm;
    else        *(f32x4*)&zcc[row][(cg-4)*4] = sm;
  }
  #pragma unroll
  for (int i=0;i<4;i++){
    int idx = tid + i*256;
    int row = idx >> 5, ch = idx & 31;
    *(uint4*)&u_s[row][ch*8]  = *(const uint4*)(u_bf + (rowbase + row)*Hh + hq*256 + ch*8);
    *(uint4*)&v_s[row][ch*8]  = *(const uint4*)(v_bf + (rowbase + row)*Hh + hq*256 + ch*8);
  }
  float gv = g[h];
  float x_[Ss];
  size_t base = ((size_t)bc*Ss)*Hh + h;
  #pragma unroll
  for (int s=0;s<Ss;s++) x_[s] = bf2f(xinit[base + (size_t)s*Hh]);
  __syncthreads();
  size_t rowidx = rowbase*Hh + h;
  for (int tt=0; tt<Tt; ++tt){
    float u  = bf2f(u_s[tt][tid]);
    float vv = bf2f(v_s[tt][tid]);
    float dtv = __half2float(dt_in[rowidx]);
    float e1  = __expf(-dtv);
    float dtu = dtv*u;
    float a2 = e1*e1;
    float a4 = a2*a2;
    float w0=e1, w1=a2, w2=a2*e1, w3=a4;
    float y0=0.f,y1=0.f,y2=0.f,y3=0.f;
    #pragma unroll
    for (int grp=0; grp<4; ++grp){
      int s0 = grp*4;
      f32x4 bv = *(const f32x4*)&zb[tt][s0];
      f32x4 cv = *(const f32x4*)&zcc[tt][s0];
      x_[s0+0] = fmaf(w0, x_[s0+0], dtu*bv[0]);
      x_[s0+1] = fmaf(w1, x_[s0+1], dtu*bv[1]);
      x_[s0+2] = fmaf(w2, x_[s0+2], dtu*bv[2]);
      x_[s0+3] = fmaf(w3, x_[s0+3], dtu*bv[3]);
      y0 = fmaf(x_[s0+0], cv[0], y0);
      y1 = fmaf(x_[s0+1], cv[1], y1);
      y2 = fmaf(x_[s0+2], cv[2], y2);
      y3 = fmaf(x_[s0+3], cv[3], y3);
      if (grp < 3){ w0*=a4; w1*=a4; w2*=a4; w3*=a4; }
    }
    float y = (y0+y1)+(y2+y3);
    yv[rowidx] = f2bf((y + u*gv) * fsilu(vv));
    rowidx += Hh;
  }
}

extern "C" void kernel_launch(void* const* d_in, const int* in_sizes, int n_in,
                              void* d_out, int out_size, void* d_ws, size_t ws_size,
                              hipStream_t stream) {
  const float* x      = (const float*)d_in[0];
  const float* ctx    = (const float*)d_in[1];
  const float* Wa     = (const float*)d_in[2];
  const float* ba     = (const float*)d_in[3];
  const float* conv_w = (const float*)d_in[4];
  const float* conv_b = (const float*)d_in[5];
  const float* Wc     = (const float*)d_in[6];
  const float* We     = (const float*)d_in[7];
  const float* be     = (const float*)d_in[8];
  const float* g      = (const float*)d_in[10];
  const float* Wi     = (const float*)d_in[11];
  const float* bi     = (const float*)d_in[12];
  const float* ln_w   = (const float*)d_in[13];
  const float* ln_b   = (const float*)d_in[14];
  const float* Wgb    = (const float*)d_in[15];
  const float* bgb    = (const float*)d_in[16];
  const float* Wgc    = (const float*)d_in[17];
  const float* bgc    = (const float*)d_in[18];
  float* out = (float*)d_out;

  // workspace layout (f32 element units):
  //  [ 0.. 4M)   u_pre_bf (8M bf16); yv_bf overlays after conv consumes it
  //  [ 4.. 8M)   v_bf     (8M bf16)
  //  [ 8..12M)   u_bf     (8M bf16)
  //  [12.5..13M) P1 f32 [B,NC,H]
  //  [13..15M)   Xl bf16 [B,NC,S,H]
  //  [17..18M)   Pg f32
  //  [18..19M)   Xg f32
  //  [19..21M)   Cp f32 [4][M][64]
  //  [22..26M)   act bf16 [M,1024]
  //  [26..27.4M) weight bf16 pool
  //  [28..32M)   dt fp16 [M,H]
  //  [32..32.02M) We fp16 [1024,32]
  const size_t MEG = 1024*1024;
  float*  ws       = (float*)d_ws;
  ushort* u_pre_bf = (ushort*)(ws);
  ushort* yv_bf    = (ushort*)(ws);
  ushort* v_bf     = (ushort*)(ws + 4*MEG);
  ushort* u_bf     = (ushort*)(ws + 8*MEG);
  float*  P1b      = ws + 12*MEG + MEG/2;
  ushort* Xl       = (ushort*)(ws + 13*MEG);
  float*  Pg       = ws + 17*MEG;
  float*  Xg       = ws + 18*MEG;
  float*  Cp       = ws + 19*MEG;
  ushort* act      = (ushort*)(ws + 22*MEG);
  ushort* wbf      = (ushort*)(ws + 26*MEG);
  __half* dt_h     = (__half*)(ws + 28*MEG);
  _Float16* we_h   = (_Float16*)(ws + 32*MEG);

  // fused prep: cast_x | ln | weight casts | We fp16
  prep_kernel<<<8800, 256, 0, stream>>>(
      x, ctx, ln_w, ln_b, Wa, Wgb, Wgc, Wc, Wi, We, act, wbf, we_h);
  // merged u/v GEMM: 8 waves, BM=256, XCD-swizzled 1-D grid
  gemm_uv64<<<1024, 512, 0, stream>>>(act, wbf, ba, bgb, bgc, u_pre_bf, v_bf);
  // causal depthwise conv + silu
  conv_kernel<<<(Mm*Hh/8)/256, 256, 0, stream>>>(u_pre_bf, conv_w, conv_b, u_bf);
  // zc split-K partials (summed in scan staging)
  gemm_n64s<<<dim3(Mm/128, 4), 256, 0, stream>>>(u_bf, wbf+OFF_Wc, Cp);
  // chunk-parallel scan with fused fp16 dt-dot + hierarchical combine
  scanA_kernel<<<(Bb*NCc*Hh)/256, 256, 0, stream>>>(u_bf, Cp, we_h, be, P1b, Xl, dt_h);
  scanC1_kernel<<<Bb*NGg*Ss*4, 256, 0, stream>>>(P1b, Xl, Pg, Xg);
  scanC2_kernel<<<(Bb*Ss*Hh)/256, 256, 0, stream>>>(Pg, Xg);
  scanC3_kernel<<<Bb*NGg*Ss*4, 256, 0, stream>>>(P1b, Xg, Xl);
  scanB_kernel<<<(Bb*NCc*Hh)/256, 256, 0, stream>>>(u_bf, Cp, dt_h, v_bf, g, Xl, yv_bf);
  // out = yv @ Wi^T + bi  (XCD-swizzled 1-D grid)
  gemm_out64<<<512, 256, 0, stream>>>(yv_bf, wbf+OFF_Wi, bi, out);
}